// Round 13
// baseline (93.473 us; speedup 1.0000x reference)
//
#include <hip/hip_runtime.h>
#include <stdint.h>

// DIAGNOSTIC ROUND (r13). A and B are VERBATIM r12 (best, 19.27us).
// Kernel C measures the machine's pure cold-read ceiling in the harness's
// real state (L3 fully dirty with 0xAA ws lines): grid-stride nt reads of
// 224 MiB of ws, TWICE. It lands rank-1 in top-5 -> exposes hbm_gbps and
// FETCH_SIZE for a pure read stream. FETCH ~448 MiB => nt bypasses L3;
// FETCH ~224-300 MiB => nt allocates (pass 2 was cached).

typedef float f4 __attribute__((ext_vector_type(4)));

constexpr int B    = 32;
constexpr int I    = 1024;
constexpr int DIN  = 512;
constexpr int K    = 512;
constexpr int CHUNKS = 16;
constexpr int ROWS   = I / CHUNKS;   // 64

// ---------------- Kernel C: pure-read benchmark ----------------
constexpr size_t C_BYTES = 224ull << 20;   // bytes per pass
constexpr int    C_GRID  = 2048;

__global__ __launch_bounds__(512) void readbench_kernel(
    const float* __restrict__ base) {
  const f4* p = reinterpret_cast<const f4*>(base);
  const size_t n4     = C_BYTES / 16;
  const size_t tid    = (size_t)blockIdx.x * 512 + threadIdx.x;
  const size_t stride = (size_t)C_GRID * 512;
  f4 s = (f4)(0.f);
  #pragma unroll 1
  for (int pass = 0; pass < 2; ++pass) {
    #pragma unroll 4
    for (size_t i = tid; i < n4; i += stride)
      s += __builtin_nontemporal_load(p + i);
    asm volatile("" ::: "memory");
  }
  asm volatile("" :: "v"(s.x), "v"(s.y), "v"(s.z), "v"(s.w));
}

// ---------------- Kernel A: verbatim r12/r11 ----------------
__global__ __launch_bounds__(512) void colsum_kernel(
    const float* __restrict__ u, float* __restrict__ P) {
  const int b     = blockIdx.x >> 4;
  const int chunk = blockIdx.x & 15;
  const int t     = threadIdx.x;
  const int p     = t >> 7;
  const int c4    = t & 127;

  __shared__ f4 Uh[4][DIN / 4];

  const float* base =
      u + ((size_t)b * I + (size_t)chunk * ROWS + p) * DIN + 4 * (size_t)c4;
  uint64_t a  = (uint64_t)base;
  uint64_t st = 4ull * DIN * sizeof(float);

  f4 d0, d1, d2, d3, d4, d5, d6, d7, d8, d9, d10, d11, d12, d13, d14, d15;
  asm volatile(
      "global_load_dwordx4 %[d0],  %[a], off sc1 nt\n\t"
      "v_lshl_add_u64 %[a], %[st], 0, %[a]\n\t"
      "global_load_dwordx4 %[d1],  %[a], off sc1 nt\n\t"
      "v_lshl_add_u64 %[a], %[st], 0, %[a]\n\t"
      "global_load_dwordx4 %[d2],  %[a], off sc1 nt\n\t"
      "v_lshl_add_u64 %[a], %[st], 0, %[a]\n\t"
      "global_load_dwordx4 %[d3],  %[a], off sc1 nt\n\t"
      "v_lshl_add_u64 %[a], %[st], 0, %[a]\n\t"
      "global_load_dwordx4 %[d4],  %[a], off sc1 nt\n\t"
      "v_lshl_add_u64 %[a], %[st], 0, %[a]\n\t"
      "global_load_dwordx4 %[d5],  %[a], off sc1 nt\n\t"
      "v_lshl_add_u64 %[a], %[st], 0, %[a]\n\t"
      "global_load_dwordx4 %[d6],  %[a], off sc1 nt\n\t"
      "v_lshl_add_u64 %[a], %[st], 0, %[a]\n\t"
      "global_load_dwordx4 %[d7],  %[a], off sc1 nt\n\t"
      "v_lshl_add_u64 %[a], %[st], 0, %[a]\n\t"
      "global_load_dwordx4 %[d8],  %[a], off sc1 nt\n\t"
      "v_lshl_add_u64 %[a], %[st], 0, %[a]\n\t"
      "global_load_dwordx4 %[d9],  %[a], off sc1 nt\n\t"
      "v_lshl_add_u64 %[a], %[st], 0, %[a]\n\t"
      "global_load_dwordx4 %[d10], %[a], off sc1 nt\n\t"
      "v_lshl_add_u64 %[a], %[st], 0, %[a]\n\t"
      "global_load_dwordx4 %[d11], %[a], off sc1 nt\n\t"
      "v_lshl_add_u64 %[a], %[st], 0, %[a]\n\t"
      "global_load_dwordx4 %[d12], %[a], off sc1 nt\n\t"
      "v_lshl_add_u64 %[a], %[st], 0, %[a]\n\t"
      "global_load_dwordx4 %[d13], %[a], off sc1 nt\n\t"
      "v_lshl_add_u64 %[a], %[st], 0, %[a]\n\t"
      "global_load_dwordx4 %[d14], %[a], off sc1 nt\n\t"
      "v_lshl_add_u64 %[a], %[st], 0, %[a]\n\t"
      "global_load_dwordx4 %[d15], %[a], off sc1 nt\n\t"
      "s_waitcnt vmcnt(0)"
      : [d0] "=&v"(d0), [d1] "=&v"(d1), [d2] "=&v"(d2), [d3] "=&v"(d3),
        [d4] "=&v"(d4), [d5] "=&v"(d5), [d6] "=&v"(d6), [d7] "=&v"(d7),
        [d8] "=&v"(d8), [d9] "=&v"(d9), [d10] "=&v"(d10), [d11] "=&v"(d11),
        [d12] "=&v"(d12), [d13] "=&v"(d13), [d14] "=&v"(d14),
        [d15] "=&v"(d15), [a] "+v"(a)
      : [st] "v"(st)
      : "memory");

  f4 s = d0;
  s += d1;  s += d2;  s += d3;  s += d4;  s += d5;  s += d6;  s += d7;
  s += d8;  s += d9;  s += d10; s += d11; s += d12; s += d13; s += d14;
  s += d15;

  Uh[p][c4] = s;
  __syncthreads();
  if (t < DIN / 4) {
    f4 r4 = (Uh[0][t] + Uh[1][t]) + (Uh[2][t] + Uh[3][t]);
    reinterpret_cast<f4*>(P + ((size_t)b * CHUNKS + chunk) * DIN)[t] = r4;
  }
}

// ---------------- Kernel B: verbatim r12 ----------------
__global__ __launch_bounds__(256) void gemm_kernel(
    const float* __restrict__ P, const float* __restrict__ W,
    float* __restrict__ out) {
  const int b  = blockIdx.x >> 3;
  const int k0 = (blockIdx.x & 7) * 64;
  const int t  = threadIdx.x;

  __shared__ float U[DIN];
  __shared__ f4    Uh[2][DIN / 4];
  __shared__ f4    red[16][16];

  const int kc = t & 15;
  const int dg = t >> 4;
  const f4* W4 = reinterpret_cast<const f4*>(W) + (size_t)(k0 >> 2) + kc;
  f4 w[32];
  #pragma unroll
  for (int d = 0; d < 32; ++d)
    w[d] = W4[(size_t)(dg * 32 + d) * (K / 4)];

  const f4* P4 = reinterpret_cast<const f4*>(P + (size_t)b * CHUNKS * DIN);
  const int col = t & 127, half = t >> 7;
  f4 s = (f4)(0.f);
  #pragma unroll
  for (int c = 0; c < CHUNKS / 2; ++c)
    s += P4[(size_t)(half * (CHUNKS / 2) + c) * (DIN / 4) + col];
  Uh[half][col] = s;
  __syncthreads();
  if (t < DIN / 4) {
    f4 a = Uh[0][t] + Uh[1][t];
    U[4 * t + 0] = a.x;
    U[4 * t + 1] = a.y;
    U[4 * t + 2] = a.z;
    U[4 * t + 3] = a.w;
  }
  __syncthreads();

  f4 acc = (f4)(0.f);
  #pragma unroll
  for (int d = 0; d < 32; ++d)
    acc += U[dg * 32 + d] * w[d];
  red[dg][kc] = acc;
  __syncthreads();

  if (t < 64) {
    const int c = t >> 2, comp = t & 3;
    float r = 0.f;
    #pragma unroll
    for (int g = 0; g < 16; ++g) r += red[g][c][comp];
    out[(size_t)b * K + k0 + t] = r;
  }
}

extern "C" void kernel_launch(void* const* d_in, const int* in_sizes, int n_in,
                              void* d_out, int out_size, void* d_ws, size_t ws_size,
                              hipStream_t stream) {
  const float* u = (const float*)d_in[0];   // [32,1024,512] f32
  const float* W = (const float*)d_in[1];   // [1,512,512]   f32
  float* out = (float*)d_out;               // [32,32,16]    f32
  float* P   = (float*)d_ws;                // [32][16][512] f32 = 1 MiB

  // Diagnostic pure-read benchmark over ws (offset 16 MiB, clear of P).
  const float* rb = (const float*)((char*)d_ws + (16ull << 20));
  readbench_kernel<<<C_GRID, 512, 0, stream>>>(rb);

  colsum_kernel<<<B * CHUNKS, 512, 0, stream>>>(u, P);
  gemm_kernel<<<B * 8, 256, 0, stream>>>(P, W, out);
}

// Round 14
// 19.554 us; speedup vs baseline: 4.7801x; 4.7801x over previous
//
#include <hip/hip_runtime.h>
#include <stdint.h>

// o[b,k] = sum_din (sum_i u[b,i,din]) * W[din,k]  (routing collapses; see r0).
// FINAL (r12 best, 19.27us, restored after r13 diagnostic).
// Ceiling evidence (r13 readbench reference): machine's pure cold-read rate
// with maximal parallelism = 3.5-4.5 TB/s (vs 6.7 TB/s store rate of the
// poison fills). A runs at ~4.4 TB/s on its mandatory 64 MiB of u reads ->
// at the wall. Composed floor: 14.9 (A) + ~1.5 (B) + ~2.4 (launch) ~= 18.8us;
// measured 19.27us (~2.5% off). Fusion ruled out (r5/r6: cross-block handoff
// 3-6x slower on non-coherent-L2 hw). Occupancy/stream-count/cache-policy
// knobs all null (r2/r4/r8/r10/r11).

typedef float f4 __attribute__((ext_vector_type(4)));

constexpr int B    = 32;
constexpr int I    = 1024;
constexpr int DIN  = 512;
constexpr int K    = 512;            // NUM_CAPSULE * DIM_CAPSULE
constexpr int CHUNKS = 16;           // 512 blocks, 128-KB slabs
constexpr int ROWS   = I / CHUNKS;   // 64 rows per chunk

// Kernel A: P[b][chunk][din] = sum_{r in chunk} u[b][chunk*ROWS + r][din]
// 512 threads: row-slot p = t>>7 (0..3), f4-col c4 = t&127.
// 16 sc1-nt dwordx4 loads issued back-to-back from one asm block
// (single vmcnt(0) at the end of the same block -> no hoist hazard).
__global__ __launch_bounds__(512) void colsum_kernel(
    const float* __restrict__ u, float* __restrict__ P) {
  const int b     = blockIdx.x >> 4;
  const int chunk = blockIdx.x & 15;
  const int t     = threadIdx.x;
  const int p     = t >> 7;
  const int c4    = t & 127;

  __shared__ f4 Uh[4][DIN / 4];

  const float* base =
      u + ((size_t)b * I + (size_t)chunk * ROWS + p) * DIN + 4 * (size_t)c4;
  uint64_t a  = (uint64_t)base;
  uint64_t st = 4ull * DIN * sizeof(float);

  f4 d0, d1, d2, d3, d4, d5, d6, d7, d8, d9, d10, d11, d12, d13, d14, d15;
  asm volatile(
      "global_load_dwordx4 %[d0],  %[a], off sc1 nt\n\t"
      "v_lshl_add_u64 %[a], %[st], 0, %[a]\n\t"
      "global_load_dwordx4 %[d1],  %[a], off sc1 nt\n\t"
      "v_lshl_add_u64 %[a], %[st], 0, %[a]\n\t"
      "global_load_dwordx4 %[d2],  %[a], off sc1 nt\n\t"
      "v_lshl_add_u64 %[a], %[st], 0, %[a]\n\t"
      "global_load_dwordx4 %[d3],  %[a], off sc1 nt\n\t"
      "v_lshl_add_u64 %[a], %[st], 0, %[a]\n\t"
      "global_load_dwordx4 %[d4],  %[a], off sc1 nt\n\t"
      "v_lshl_add_u64 %[a], %[st], 0, %[a]\n\t"
      "global_load_dwordx4 %[d5],  %[a], off sc1 nt\n\t"
      "v_lshl_add_u64 %[a], %[st], 0, %[a]\n\t"
      "global_load_dwordx4 %[d6],  %[a], off sc1 nt\n\t"
      "v_lshl_add_u64 %[a], %[st], 0, %[a]\n\t"
      "global_load_dwordx4 %[d7],  %[a], off sc1 nt\n\t"
      "v_lshl_add_u64 %[a], %[st], 0, %[a]\n\t"
      "global_load_dwordx4 %[d8],  %[a], off sc1 nt\n\t"
      "v_lshl_add_u64 %[a], %[st], 0, %[a]\n\t"
      "global_load_dwordx4 %[d9],  %[a], off sc1 nt\n\t"
      "v_lshl_add_u64 %[a], %[st], 0, %[a]\n\t"
      "global_load_dwordx4 %[d10], %[a], off sc1 nt\n\t"
      "v_lshl_add_u64 %[a], %[st], 0, %[a]\n\t"
      "global_load_dwordx4 %[d11], %[a], off sc1 nt\n\t"
      "v_lshl_add_u64 %[a], %[st], 0, %[a]\n\t"
      "global_load_dwordx4 %[d12], %[a], off sc1 nt\n\t"
      "v_lshl_add_u64 %[a], %[st], 0, %[a]\n\t"
      "global_load_dwordx4 %[d13], %[a], off sc1 nt\n\t"
      "v_lshl_add_u64 %[a], %[st], 0, %[a]\n\t"
      "global_load_dwordx4 %[d14], %[a], off sc1 nt\n\t"
      "v_lshl_add_u64 %[a], %[st], 0, %[a]\n\t"
      "global_load_dwordx4 %[d15], %[a], off sc1 nt\n\t"
      "s_waitcnt vmcnt(0)"
      : [d0] "=&v"(d0), [d1] "=&v"(d1), [d2] "=&v"(d2), [d3] "=&v"(d3),
        [d4] "=&v"(d4), [d5] "=&v"(d5), [d6] "=&v"(d6), [d7] "=&v"(d7),
        [d8] "=&v"(d8), [d9] "=&v"(d9), [d10] "=&v"(d10), [d11] "=&v"(d11),
        [d12] "=&v"(d12), [d13] "=&v"(d13), [d14] "=&v"(d14),
        [d15] "=&v"(d15), [a] "+v"(a)
      : [st] "v"(st)
      : "memory");

  f4 s = d0;
  s += d1;  s += d2;  s += d3;  s += d4;  s += d5;  s += d6;  s += d7;
  s += d8;  s += d9;  s += d10; s += d11; s += d12; s += d13; s += d14;
  s += d15;

  Uh[p][c4] = s;
  __syncthreads();
  if (t < DIN / 4) {
    f4 r4 = (Uh[0][t] + Uh[1][t]) + (Uh[2][t] + Uh[3][t]);
    reinterpret_cast<f4*>(P + ((size_t)b * CHUNKS + chunk) * DIN)[t] = r4;
  }
}

// Kernel B: W loads hoisted above stage-1 barrier (latency overlap, r12);
// stage 2 pure VALU/LDS. grid = B*8 blocks (64-wide k-tiles), 256 threads.
__global__ __launch_bounds__(256) void gemm_kernel(
    const float* __restrict__ P, const float* __restrict__ W,
    float* __restrict__ out) {
  const int b  = blockIdx.x >> 3;
  const int k0 = (blockIdx.x & 7) * 64;
  const int t  = threadIdx.x;

  __shared__ float U[DIN];
  __shared__ f4    Uh[2][DIN / 4];
  __shared__ f4    red[16][16];

  // W prefetch: thread (dg, kc) owns 32 rows x one f4-col; 32 independent
  // loads complete under stage-1's P-read latency.
  const int kc = t & 15;
  const int dg = t >> 4;
  const f4* W4 = reinterpret_cast<const f4*>(W) + (size_t)(k0 >> 2) + kc;
  f4 w[32];
  #pragma unroll
  for (int d = 0; d < 32; ++d)
    w[d] = W4[(size_t)(dg * 32 + d) * (K / 4)];

  // Stage 1: U[b] = sum_c P[b][c]
  const f4* P4 = reinterpret_cast<const f4*>(P + (size_t)b * CHUNKS * DIN);
  const int col = t & 127, half = t >> 7;
  f4 s = (f4)(0.f);
  #pragma unroll
  for (int c = 0; c < CHUNKS / 2; ++c)
    s += P4[(size_t)(half * (CHUNKS / 2) + c) * (DIN / 4) + col];
  Uh[half][col] = s;
  __syncthreads();
  if (t < DIN / 4) {
    f4 a = Uh[0][t] + Uh[1][t];
    U[4 * t + 0] = a.x;
    U[4 * t + 1] = a.y;
    U[4 * t + 2] = a.z;
    U[4 * t + 3] = a.w;
  }
  __syncthreads();

  // Stage 2: pure VALU — acc[kc] = sum_{d in dg} U[d] * w[d]
  f4 acc = (f4)(0.f);
  #pragma unroll
  for (int d = 0; d < 32; ++d)
    acc += U[dg * 32 + d] * w[d];
  red[dg][kc] = acc;
  __syncthreads();

  // Cross-dg reduce: 64 threads, k = k0 + t
  if (t < 64) {
    const int c = t >> 2, comp = t & 3;
    float r = 0.f;
    #pragma unroll
    for (int g = 0; g < 16; ++g) r += red[g][c][comp];
    out[(size_t)b * K + k0 + t] = r;
  }
}

extern "C" void kernel_launch(void* const* d_in, const int* in_sizes, int n_in,
                              void* d_out, int out_size, void* d_ws, size_t ws_size,
                              hipStream_t stream) {
  const float* u = (const float*)d_in[0];   // [32,1024,512] f32
  const float* W = (const float*)d_in[1];   // [1,512,512]   f32
  float* out = (float*)d_out;               // [32,32,16]    f32
  float* P   = (float*)d_ws;                // [32][16][512] f32 = 1 MiB

  colsum_kernel<<<B * CHUNKS, 512, 0, stream>>>(u, P);
  gemm_kernel<<<B * 8, 256, 0, stream>>>(P, W, out);
}